// Round 5
// baseline (128.965 us; speedup 1.0000x reference)
//
#include <hip/hip_runtime.h>
#include <hip/hip_bf16.h>

// Problem constants (fixed by the reference setup)
constexpr int   kB    = 2048;    // rows in feats
constexpr int   kC    = 256;     // feature dim
constexpr int   kG    = 128;     // group size = topk * num_instances
constexpr int   kKg   = 128;     // number of label groups
constexpr float kEps  = 1e-6f;
constexpr float kInvT = 20.0f;   // 1/0.05

constexpr int kNA = kB  * kC;    // 524288  feats elements
constexpr int kNB = kB * 8 * kC; // 4194304 feats_s elements

typedef short bf16x8 __attribute__((ext_vector_type(8)));   // 8 bf16 in 4 VGPRs
typedef float floatx4 __attribute__((ext_vector_type(4)));  // MFMA accumulator

__device__ __forceinline__ unsigned short bf16_rne(float x) {
    union { float f; unsigned int u; } c; c.f = x;
    unsigned int r = c.u + 0x7FFFu + ((c.u >> 16) & 1u);
    return (unsigned short)(r >> 16);
}

// Direct global -> LDS DMA, 16 B per lane. LDS dest must be the
// wave-uniform base (HW adds lane*16); global src is per-lane.
__device__ __forceinline__ void gload_lds16(const __hip_bfloat16* g,
                                            __hip_bfloat16* l) {
    __builtin_amdgcn_global_load_lds(
        (const __attribute__((address_space(1))) unsigned int*)g,
        (__attribute__((address_space(3))) unsigned int*)l, 16, 0, 0);
}

// Kernel 1: fp32 -> bf16 pre-convert (once), and zero pos_e/neg_e.
__global__ __launch_bounds__(256) void convert_kernel(
    const float* __restrict__ feats,    // [2048,256] fp32
    const float* __restrict__ feats_s,  // [16384,256] fp32
    __hip_bfloat16* __restrict__ fa,    // [2048,256] bf16 out
    __hip_bfloat16* __restrict__ fb,    // [16384,256] bf16 out
    float* __restrict__ zero_area)      // pos[2048], neg[2048]
{
    int gid = blockIdx.x * 256 + threadIdx.x;
    if (gid < 2 * kB) zero_area[gid] = 0.0f;

    size_t base = (size_t)gid * 8;
    const float* src; __hip_bfloat16* dst; size_t off;
    if (base < (size_t)kNA) { src = feats;   dst = fa; off = base; }
    else                    { src = feats_s; dst = fb; off = base - kNA; }
    float4 v0 = *(const float4*)(src + off);
    float4 v1 = *(const float4*)(src + off + 4);
    unsigned short u[8];
    u[0] = bf16_rne(v0.x); u[1] = bf16_rne(v0.y);
    u[2] = bf16_rne(v0.z); u[3] = bf16_rne(v0.w);
    u[4] = bf16_rne(v1.x); u[5] = bf16_rne(v1.y);
    u[6] = bf16_rne(v1.z); u[7] = bf16_rne(v1.w);
    *(uint4*)(dst + off) = *(const uint4*)u;
}

// Kernel 2 (R15 = R14 pipeline, LDS cut to the 128 KiB envelope):
// persistent-B deep pipeline. 256 blocks (128 groups x 2 row-halves),
// 8 waves = 8 row-slices of 64 rows x full 128 cols (acc[4][8]).
// Per-row min/max is now ENTIRELY in-wave -> no rmin/rmax LDS (the 8 KB
// that pushed R11/R14 past 128 KiB static LDS and killed the launch).
// B-tile [128][256] full-K resident in LDS (loaded once); A streamed as
// 16 chunks of [512 rows][32 k] double-buffered via linear gload_lds.
// Counted vmcnt(4): chunk i+2 issued before the wait for i+1; never
// drain vmcnt(0) in the main loop (T3+T4). Both-sides XOR swizzle
// (pre-swizzled GLOBAL src + matching XOR on ds_read, rule #21):
//   A granule q' = q ^ ((row>>1)&3)  -> 2-way bank access (free, m136)
//   B granule q' = q ^ (row&7)       -> 2-way bank access (free)
// Retired levers (do NOT reintroduce):
//  - static LDS > 128 KiB: launch fails on this harness (R11, R14).
//  - 2-phase stage/drain loop at any tile size: 40-60 µs, MfmaUtil <15%
//    (R7/R12/R13 — the drained-barrier structure is the bottleneck).
//  - per-kk register prefetch inside the MFMA loop: spills (R5/R8/R9).
//  - permuted-lane LDS dest for global_load_lds: breaks DMA (R4).
//  - fused finalize w/ per-block __threadfence: +120 µs (R10).
__global__ __launch_bounds__(512, 2) void sim_minmax_kernel(
    const __hip_bfloat16* __restrict__ fa,   // [2048,256] bf16
    const __hip_bfloat16* __restrict__ fb,   // [16384,256] bf16
    const int* __restrict__ labels,          // [2048]
    const int* __restrict__ labels_s,        // [16384]
    float* __restrict__ pos_e,               // [2048]
    float* __restrict__ neg_e)               // [2048]
{
    const int g  = blockIdx.x;          // 0..127 label group
    const int h  = blockIdx.y;          // 0..1 row half (1024 rows)
    const int n0 = g * kG;

    __shared__ alignas(16) __hip_bfloat16 Bs[128 * 256];    // 64 KB, full K
    __shared__ alignas(16) __hip_bfloat16 As[2][512 * 32];  // 2 x 32 KB
    // total static LDS = 131072 B exactly (the verified envelope)

    const int t    = threadIdx.x;
    const int wave = t >> 6;      // row slice (0..7): 64 rows each
    const int lane = t & 63;
    const int l15  = lane & 15;
    const int quad = lane >> 4;

    floatx4 acc[4][8];

    // Stage one A chunk (512 rows x 32 k = 2048 granules, 4/thread).
    // LDS linear (DMA requirement); global src pre-swizzled so the
    // read-side XOR sees logical data. Each row's 4 granules form one
    // 64B line -> the permutation is free for coalescing.
    auto stageA = [&](int chunk, int buf) {
        const int rbase = h * 1024 + (chunk >> 3) * 512;
        const int kbase = (chunk & 7) * 32;
#pragma unroll
        for (int j = 0; j < 4; j++) {
            int c = t + 512 * j;
            int r = c >> 2, qp = c & 3;
            int q = qp ^ ((r >> 1) & 3);
            gload_lds16(fa + (size_t)(rbase + r) * kC + kbase + q * 8,
                        &As[buf][((t & ~63) + 512 * j) * 8]);
        }
    };

    auto compute = [&](int buf, int ki) {
        bf16x8 a[4], b[8];
#pragma unroll
        for (int nt = 0; nt < 8; nt++) {
            int rB = nt * 16 + l15;
            int q  = (ki * 4 + quad) ^ (rB & 7);
            b[nt] = *(const bf16x8*)(&Bs[rB * 256 + q * 8]);
        }
#pragma unroll
        for (int mt = 0; mt < 4; mt++) {
            int rA = wave * 64 + mt * 16 + l15;
            int sw = quad ^ ((rA >> 1) & 3);
            a[mt] = *(const bf16x8*)(&As[buf][rA * 32 + sw * 8]);
        }
        __builtin_amdgcn_s_setprio(1);
#pragma unroll
        for (int mt = 0; mt < 4; mt++)
#pragma unroll
            for (int nt = 0; nt < 8; nt++)
                acc[mt][nt] = __builtin_amdgcn_mfma_f32_16x16x32_bf16(
                    a[mt], b[nt], acc[mt][nt], 0, 0, 0);
        __builtin_amdgcn_s_setprio(0);
    };

    // ---- prologue: B (4096 granules, 8/thread), then A chunks 0,1 ----
#pragma unroll
    for (int j = 0; j < 8; j++) {
        int c = t + 512 * j;
        int r = c >> 5, qp = c & 31;
        int q = qp ^ (r & 7);
        gload_lds16(fb + (size_t)(n0 + r) * kC + q * 8,
                    &Bs[((t & ~63) + 512 * j) * 8]);
    }
    stageA(0, 0);
    stageA(1, 1);
    // B(8) + A0(4) done; A1's 4 may remain in flight.
    asm volatile("s_waitcnt vmcnt(4)" ::: "memory");
    __builtin_amdgcn_s_barrier();
    asm volatile("" ::: "memory");

    const int lbl = labels_s[n0];

    for (int rp = 0; rp < 2; rp++) {
#pragma unroll
        for (int mt = 0; mt < 4; mt++)
#pragma unroll
            for (int nt = 0; nt < 8; nt++)
                acc[mt][nt] = (floatx4){0.f, 0.f, 0.f, 0.f};

        for (int ki = 0; ki < 8; ki++) {
            const int i = rp * 8 + ki;
            const int b = i & 1;
            compute(b, ki);
            __builtin_amdgcn_s_barrier();          // all waves done with A[b]
            if (i + 2 < 16) {
                stageA(i + 2, b);                  // refill the freed buffer
                // chunk i+1 (issued last iter) landed; i+2's 4 stay in flight
                asm volatile("s_waitcnt vmcnt(4)" ::: "memory");
            } else {
                asm volatile("s_waitcnt vmcnt(0)" ::: "memory");
            }
            __builtin_amdgcn_s_barrier();          // everyone's i+1 visible
            asm volatile("" ::: "memory");
        }

        // ---- epilogue for this 512-row phase: fully in-wave ----
        // D layout: col = lane&15, row = quad*4 + reg within each 16x16.
        // Row min/max = fmin/fmax over 8 nt tiles + 16-lane shfl reduce.
#pragma unroll
        for (int mt = 0; mt < 4; mt++) {
#pragma unroll
            for (int reg = 0; reg < 4; reg++) {
                float vn = acc[mt][0][reg], vx = acc[mt][0][reg];
#pragma unroll
                for (int nt = 1; nt < 8; nt++) {
                    vn = fminf(vn, acc[mt][nt][reg]);
                    vx = fmaxf(vx, acc[mt][nt][reg]);
                }
#pragma unroll
                for (int s = 1; s < 16; s <<= 1) {
                    vn = fminf(vn, __shfl_xor(vn, s, 64));
                    vx = fmaxf(vx, __shfl_xor(vx, s, 64));
                }
                if (l15 == 0) {
                    int gb = h * 1024 + rp * 512 + wave * 64 + mt * 16
                           + quad * 4 + reg;
                    if (labels[gb] == lbl) {
                        pos_e[gb] = __expf(vn * kInvT);   // unique writer
                    } else {
                        atomicAdd(&neg_e[gb], __expf(vx * kInvT));
                    }
                }
            }
        }
        // no LDS used in the epilogue -> no extra barrier; the ki-loop
        // barriers protect the As double-buffer across the rp boundary.
    }
}

// Kernel 3: per-row loss + mean over 2048 rows -> single fp32 scalar.
__global__ void finalize_kernel(const float* __restrict__ pos_e,
                                const float* __restrict__ neg_e,
                                float* __restrict__ out)
{
    __shared__ float red[256];
    float s = 0.f;
    for (int r = threadIdx.x; r < kB; r += 256) {
        float p = pos_e[r];
        float n = neg_e[r];
        s += -__logf(p / (p + n + kEps) + kEps);
    }
    red[threadIdx.x] = s;
    __syncthreads();
    for (int off = 128; off > 0; off >>= 1) {
        if (threadIdx.x < off) red[threadIdx.x] += red[threadIdx.x + off];
        __syncthreads();
    }
    if (threadIdx.x == 0) out[0] = red[0] / (float)kB;
}

extern "C" void kernel_launch(void* const* d_in, const int* in_sizes, int n_in,
                              void* d_out, int out_size, void* d_ws, size_t ws_size,
                              hipStream_t stream) {
    (void)in_sizes; (void)n_in; (void)out_size; (void)ws_size;

    const float* feats    = (const float*)d_in[0];
    const float* feats_s  = (const float*)d_in[1];
    const int*   labels   = (const int*)d_in[2];
    const int*   labels_s = (const int*)d_in[3];
    // d_in[4] = topk (8), d_in[5] = num_instances (16) — fixed, hard-coded.

    // ws layout: pos[2048] f32 | neg[2048] f32 | pad | fa 1MB | fb 8MB
    float* pos_e = (float*)d_ws;
    float* neg_e = pos_e + kB;
    __hip_bfloat16* fa = (__hip_bfloat16*)((char*)d_ws + 32768);
    __hip_bfloat16* fb = (__hip_bfloat16*)((char*)d_ws + 32768 + (size_t)kNA * 2);

    // convert: (kNA + kNB)/8 threads = 589824 -> 2304 blocks of 256
    convert_kernel<<<(kNA + kNB) / 8 / 256, 256, 0, stream>>>(
        feats, feats_s, fa, fb, pos_e);

    dim3 grid(kKg, 2);   // 128 groups x 2 row-halves = 256 blocks (1/CU)
    sim_minmax_kernel<<<grid, 512, 0, stream>>>(
        fa, fb, labels, labels_s, pos_e, neg_e);
    finalize_kernel<<<1, 256, 0, stream>>>(pos_e, neg_e, (float*)d_out);
}

// Round 6
// 125.039 us; speedup vs baseline: 1.0314x; 1.0314x over previous
//
#include <hip/hip_runtime.h>
#include <hip/hip_bf16.h>

// Problem constants (fixed by the reference setup)
constexpr int   kB    = 2048;    // rows in feats
constexpr int   kC    = 256;     // feature dim
constexpr int   kG    = 128;     // group size = topk * num_instances
constexpr int   kKg   = 128;     // number of label groups
constexpr float kEps  = 1e-6f;
constexpr float kInvT = 20.0f;   // 1/0.05

constexpr int kNA = kB  * kC;    // 524288  feats elements
constexpr int kNB = kB * 8 * kC; // 4194304 feats_s elements

typedef short bf16x8 __attribute__((ext_vector_type(8)));   // 8 bf16 in 4 VGPRs
typedef float floatx4 __attribute__((ext_vector_type(4)));  // MFMA accumulator

__device__ __forceinline__ unsigned short bf16_rne(float x) {
    union { float f; unsigned int u; } c; c.f = x;
    unsigned int r = c.u + 0x7FFFu + ((c.u >> 16) & 1u);
    return (unsigned short)(r >> 16);
}

// Direct global -> LDS DMA, 16 B per lane. LDS dest must be the
// wave-uniform base (HW adds lane*16); global src is per-lane.
__device__ __forceinline__ void gload_lds16(const __hip_bfloat16* g,
                                            __hip_bfloat16* l) {
    __builtin_amdgcn_global_load_lds(
        (const __attribute__((address_space(1))) unsigned int*)g,
        (__attribute__((address_space(3))) unsigned int*)l, 16, 0, 0);
}

// Kernel 1: fp32 -> bf16 pre-convert (once), and zero pos_e/neg_e.
__global__ __launch_bounds__(256) void convert_kernel(
    const float* __restrict__ feats,    // [2048,256] fp32
    const float* __restrict__ feats_s,  // [16384,256] fp32
    __hip_bfloat16* __restrict__ fa,    // [2048,256] bf16 out
    __hip_bfloat16* __restrict__ fb,    // [16384,256] bf16 out
    float* __restrict__ zero_area)      // pos[2048], neg[2048]
{
    int gid = blockIdx.x * 256 + threadIdx.x;
    if (gid < 2 * kB) zero_area[gid] = 0.0f;

    size_t base = (size_t)gid * 8;
    const float* src; __hip_bfloat16* dst; size_t off;
    if (base < (size_t)kNA) { src = feats;   dst = fa; off = base; }
    else                    { src = feats_s; dst = fb; off = base - kNA; }
    float4 v0 = *(const float4*)(src + off);
    float4 v1 = *(const float4*)(src + off + 4);
    unsigned short u[8];
    u[0] = bf16_rne(v0.x); u[1] = bf16_rne(v0.y);
    u[2] = bf16_rne(v0.z); u[3] = bf16_rne(v0.w);
    u[4] = bf16_rne(v1.x); u[5] = bf16_rne(v1.y);
    u[6] = bf16_rne(v1.z); u[7] = bf16_rne(v1.w);
    *(uint4*)(dst + off) = *(const uint4*)u;
}

// Kernel 2 (R16): barrier-free independent-wave GEMM.
// Rationale (Common-mistake #7): fa (1 MB) and the per-XCD fb slice
// (~1 MB) both fit in the 4 MB XCD L2 — LDS-staging A and its per-K-step
// barriers were pure overhead (R7/R13/R15 all 40-52 µs, MfmaUtil <14%,
// ~75% no-issue cycles: all waves lockstep-stalled on the same barrier).
// New structure: B [128x256] staged ONCE per block in LDS (8-wave reuse,
// R15's verified linear-DMA + read-XOR path); A-fragments load directly
// global->VGPR (the 16x16x32 A-frag is a natural 16-row x 64B coalesced
// dwordx4 pattern, L2-resident). ONE barrier per kernel; after it the
// 8 waves are fully independent 32-row tasks -> real TLP latency hiding.
// 1024 blocks x 512 thr, 64 KB LDS -> 2 blocks/CU, target 16 waves/CU.
// Retired levers (do NOT reintroduce):
//  - static LDS > 128 KiB: launch fails on this harness (R11, R14).
//  - per-K-step barriered staging loops (2-phase OR deep counted-vmcnt):
//    40-52 µs, MfmaUtil <15% (R7/R12/R13/R15) — latency-bound lockstep.
//  - per-kk register prefetch inside the MFMA loop: spills (R5/R8/R9).
//  - permuted-lane LDS dest for global_load_lds: breaks DMA (R4).
//  - fused finalize w/ per-block __threadfence: +120 µs (R10).
__global__ __launch_bounds__(512, 4) void sim_minmax_kernel(
    const __hip_bfloat16* __restrict__ fa,   // [2048,256] bf16
    const __hip_bfloat16* __restrict__ fb,   // [16384,256] bf16
    const int* __restrict__ labels,          // [2048]
    const int* __restrict__ labels_s,        // [16384]
    float* __restrict__ pos_e,               // [2048]
    float* __restrict__ neg_e)               // [2048]
{
    const int g     = blockIdx.x;        // 0..127 label group
    const int chunk = blockIdx.y;        // 0..7 row chunk (256 rows)
    const int n0    = g * kG;

    __shared__ alignas(16) __hip_bfloat16 Bs[128 * 256];   // 64 KB, full K

    const int t    = threadIdx.x;
    const int wave = t >> 6;      // 0..7 -> rows [chunk*256 + wave*32, +32)
    const int lane = t & 63;
    const int l15  = lane & 15;
    const int quad = lane >> 4;

    // ---- B prologue (R15-verified): 4096 granules, 8/thread, linear DMA
    // with pre-swizzled global source q = qp ^ (r&7). ----
#pragma unroll
    for (int j = 0; j < 8; j++) {
        int c = t + 512 * j;
        int r = c >> 5, qp = c & 31;
        int q = qp ^ (r & 7);
        gload_lds16(fb + (size_t)(n0 + r) * kC + q * 8,
                    &Bs[((t & ~63) + 512 * j) * 8]);
    }
    asm volatile("s_waitcnt vmcnt(0)" ::: "memory");
    __builtin_amdgcn_s_barrier();            // the ONLY barrier
    asm volatile("" ::: "memory");

    const int lbl = labels_s[n0];
    const int r0  = chunk * 256 + wave * 32;   // this wave's 32 rows

    floatx4 acc[2][8];
#pragma unroll
    for (int mt = 0; mt < 2; mt++)
#pragma unroll
        for (int nt = 0; nt < 8; nt++)
            acc[mt][nt] = (floatx4){0.f, 0.f, 0.f, 0.f};

    // Per-lane A base: row = r0 + mt*16 + l15, k = ks*32 + quad*8.
    const __hip_bfloat16* aptr = fa + (size_t)(r0 + l15) * kC + quad * 8;

#pragma unroll
    for (int ks = 0; ks < 8; ks++) {
        // A-frags straight from global (L2-hit): 16 rows x 64B segments.
        bf16x8 a0 = *(const bf16x8*)(aptr + ks * 32);
        bf16x8 a1 = *(const bf16x8*)(aptr + 16 * kC + ks * 32);
        // B-frags from LDS, read-XOR matching the staged swizzle.
        bf16x8 b[8];
#pragma unroll
        for (int nt = 0; nt < 8; nt++) {
            int rB = nt * 16 + l15;
            int q  = (ks * 4 + quad) ^ (rB & 7);
            b[nt] = *(const bf16x8*)(&Bs[rB * 256 + q * 8]);
        }
        __builtin_amdgcn_s_setprio(1);
#pragma unroll
        for (int nt = 0; nt < 8; nt++) {
            acc[0][nt] = __builtin_amdgcn_mfma_f32_16x16x32_bf16(
                a0, b[nt], acc[0][nt], 0, 0, 0);
            acc[1][nt] = __builtin_amdgcn_mfma_f32_16x16x32_bf16(
                a1, b[nt], acc[1][nt], 0, 0, 0);
        }
        __builtin_amdgcn_s_setprio(0);
    }

    // ---- epilogue: fully in-wave (rows live in this wave only) ----
    // D layout: col = lane&15, row = quad*4 + reg within each 16x16 tile.
#pragma unroll
    for (int mt = 0; mt < 2; mt++) {
#pragma unroll
        for (int reg = 0; reg < 4; reg++) {
            float vn = acc[mt][0][reg], vx = acc[mt][0][reg];
#pragma unroll
            for (int nt = 1; nt < 8; nt++) {
                vn = fminf(vn, acc[mt][nt][reg]);
                vx = fmaxf(vx, acc[mt][nt][reg]);
            }
#pragma unroll
            for (int s = 1; s < 16; s <<= 1) {
                vn = fminf(vn, __shfl_xor(vn, s, 64));
                vx = fmaxf(vx, __shfl_xor(vx, s, 64));
            }
            if (l15 == 0) {
                int gb = r0 + mt * 16 + quad * 4 + reg;
                if (labels[gb] == lbl) {
                    pos_e[gb] = __expf(vn * kInvT);   // unique writer
                } else {
                    atomicAdd(&neg_e[gb], __expf(vx * kInvT));
                }
            }
        }
    }
}

// Kernel 3: per-row loss + mean over 2048 rows -> single fp32 scalar.
__global__ void finalize_kernel(const float* __restrict__ pos_e,
                                const float* __restrict__ neg_e,
                                float* __restrict__ out)
{
    __shared__ float red[256];
    float s = 0.f;
    for (int r = threadIdx.x; r < kB; r += 256) {
        float p = pos_e[r];
        float n = neg_e[r];
        s += -__logf(p / (p + n + kEps) + kEps);
    }
    red[threadIdx.x] = s;
    __syncthreads();
    for (int off = 128; off > 0; off >>= 1) {
        if (threadIdx.x < off) red[threadIdx.x] += red[threadIdx.x + off];
        __syncthreads();
    }
    if (threadIdx.x == 0) out[0] = red[0] / (float)kB;
}

extern "C" void kernel_launch(void* const* d_in, const int* in_sizes, int n_in,
                              void* d_out, int out_size, void* d_ws, size_t ws_size,
                              hipStream_t stream) {
    (void)in_sizes; (void)n_in; (void)out_size; (void)ws_size;

    const float* feats    = (const float*)d_in[0];
    const float* feats_s  = (const float*)d_in[1];
    const int*   labels   = (const int*)d_in[2];
    const int*   labels_s = (const int*)d_in[3];
    // d_in[4] = topk (8), d_in[5] = num_instances (16) — fixed, hard-coded.

    // ws layout: pos[2048] f32 | neg[2048] f32 | pad | fa 1MB | fb 8MB
    float* pos_e = (float*)d_ws;
    float* neg_e = pos_e + kB;
    __hip_bfloat16* fa = (__hip_bfloat16*)((char*)d_ws + 32768);
    __hip_bfloat16* fb = (__hip_bfloat16*)((char*)d_ws + 32768 + (size_t)kNA * 2);

    // convert: (kNA + kNB)/8 threads = 589824 -> 2304 blocks of 256
    convert_kernel<<<(kNA + kNB) / 8 / 256, 256, 0, stream>>>(
        feats, feats_s, fa, fb, pos_e);

    dim3 grid(kKg, 8);   // 128 groups x 8 row-chunks = 1024 blocks
    sim_minmax_kernel<<<grid, 512, 0, stream>>>(
        fa, fb, labels, labels_s, pos_e, neg_e);
    finalize_kernel<<<1, 256, 0, stream>>>(pos_e, neg_e, (float*)d_out);
}